// Round 1
// baseline (711.674 us; speedup 1.0000x reference)
//
#include <hip/hip_runtime.h>
#include <math.h>

#define B_ 32
#define H_ 64
#define W_ 48
#define C_ 256
#define G_ 8
#define D_ 32
#define BG_ (B_*G_)          // 256
#define LN_EPS_ 1e-3f
#define NPIX_ (H_*W_)        // 3072

__device__ __forceinline__ float sigmoidf_(float v) { return 1.0f / (1.0f + expf(-v)); }

// ---------------------------------------------------------------------------
// K1: per-group means over W and H, then 1x1 conv (d x d) + sigmoid.
// grid = BG blocks, 256 threads. Outputs xh[BG][H][32], xw[BG][W][32].
// ---------------------------------------------------------------------------
__global__ __launch_bounds__(256) void k1_means(const float* __restrict__ x,
                                                const float* __restrict__ w1,
                                                const float* __restrict__ b1,
                                                float* __restrict__ xh,
                                                float* __restrict__ xw)
{
    int bg = blockIdx.x;
    int b = bg >> 3, gi = bg & 7;
    const float* xp = x + (size_t)b * H_ * W_ * C_ + gi * D_;
    __shared__ float mh[H_][D_];
    __shared__ float mw[W_][D_];
    __shared__ float wls[D_ * D_];
    int tid = threadIdx.x;
    for (int i = tid; i < D_ * D_; i += 256) wls[i] = w1[i];
    // mean over W for each (h,c)
    for (int i = tid; i < H_ * D_; i += 256) {
        int h = i >> 5, c = i & 31;
        const float* p = xp + (size_t)h * W_ * C_ + c;
        float s = 0.f;
        for (int w = 0; w < W_; ++w) s += p[(size_t)w * C_];
        mh[h][c] = s * (1.0f / W_);
    }
    // mean over H for each (w,c)
    for (int i = tid; i < W_ * D_; i += 256) {
        int w = i >> 5, c = i & 31;
        const float* p = xp + (size_t)w * C_ + c;
        float s = 0.f;
        for (int h = 0; h < H_; ++h) s += p[(size_t)h * W_ * C_];
        mw[w][c] = s * (1.0f / H_);
    }
    __syncthreads();
    // 1x1 conv over d -> e, + bias, sigmoid
    for (int i = tid; i < (H_ + W_) * D_; i += 256) {
        int pos = i >> 5, e = i & 31;
        const float* m = (pos < H_) ? mh[pos] : mw[pos - H_];
        float acc = b1[e];
        #pragma unroll
        for (int d = 0; d < D_; ++d) acc += m[d] * wls[d * D_ + e];
        float s = sigmoidf_(acc);
        if (pos < H_) xh[((size_t)bg * H_ + pos) * D_ + e] = s;
        else          xw[((size_t)bg * W_ + (pos - H_)) * D_ + e] = s;
    }
}

// ---------------------------------------------------------------------------
// K3: 3x3 SAME conv (fp32) -> x2, fused with per-pixel x1 recompute; both are
// partial-sum reduced into s1/s2 (for the later softmaxes).
// grid = BG*16 blocks (4 rows each), 192 threads (one pixel per thread, all
// 32 output channels in registers).
// ---------------------------------------------------------------------------
__global__ __launch_bounds__(192) void k3_conv(const float* __restrict__ x,
                                               const float* __restrict__ w3,
                                               const float* __restrict__ b3,
                                               const float* __restrict__ xh,
                                               const float* __restrict__ xw,
                                               const float* __restrict__ gamma,
                                               const float* __restrict__ beta,
                                               float* __restrict__ x2,
                                               float* __restrict__ s1,
                                               float* __restrict__ s2)
{
    int bi = blockIdx.x;
    int bg = bi >> 4;
    int h0 = (bi & 15) << 2;
    int tid = threadIdx.x;
    int r = tid / W_;           // 0..3
    int w = tid % W_;
    int h = h0 + r;
    int b = bg >> 3, gi = bg & 7;
    const float* base = x + (size_t)b * H_ * W_ * C_ + gi * D_;

    float acc[D_];
    #pragma unroll
    for (int e4 = 0; e4 < 8; ++e4) {
        float4 bb = ((const float4*)b3)[e4];
        acc[4 * e4 + 0] = bb.x; acc[4 * e4 + 1] = bb.y;
        acc[4 * e4 + 2] = bb.z; acc[4 * e4 + 3] = bb.w;
    }

    #pragma unroll
    for (int dh = 0; dh < 3; ++dh) {
        int hh = h + dh - 1;
        if (hh < 0 || hh >= H_) continue;
        #pragma unroll
        for (int dw = 0; dw < 3; ++dw) {
            int ww = w + dw - 1;
            if (ww < 0 || ww >= W_) continue;
            const float4* ip = (const float4*)(base + ((size_t)hh * W_ + ww) * C_);
            const float* wt = w3 + ((dh * 3 + dw) * D_) * D_;
            for (int q = 0; q < 8; ++q) {          // rolled: keeps code small
                float4 t = ip[q];
                #pragma unroll
                for (int j = 0; j < 4; ++j) {
                    float vv = (j == 0) ? t.x : (j == 1) ? t.y : (j == 2) ? t.z : t.w;
                    const float4* wp = (const float4*)(wt + (q * 4 + j) * D_);
                    #pragma unroll
                    for (int e4 = 0; e4 < 8; ++e4) {
                        float4 wv = wp[e4];
                        acc[4 * e4 + 0] += vv * wv.x;
                        acc[4 * e4 + 1] += vv * wv.y;
                        acc[4 * e4 + 2] += vv * wv.z;
                        acc[4 * e4 + 3] += vv * wv.w;
                    }
                }
            }
        }
    }

    // store x2 pixel
    float* op = x2 + (((size_t)bg * H_ + h) * W_ + w) * D_;
    #pragma unroll
    for (int e4 = 0; e4 < 8; ++e4) {
        float4 t;
        t.x = acc[4 * e4 + 0]; t.y = acc[4 * e4 + 1];
        t.z = acc[4 * e4 + 2]; t.w = acc[4 * e4 + 3];
        ((float4*)op)[e4] = t;
    }

    int lane = tid & 63;

    // reduce x2 over the wave's 64 pixels, one atomicAdd per channel from lane 0
    #pragma unroll
    for (int e = 0; e < D_; ++e) {
        float v = acc[e];
        v += __shfl_xor(v, 1);  v += __shfl_xor(v, 2);  v += __shfl_xor(v, 4);
        v += __shfl_xor(v, 8);  v += __shfl_xor(v, 16); v += __shfl_xor(v, 32);
        acc[e] = v;
    }
    if (lane == 0) {
        #pragma unroll
        for (int e = 0; e < D_; ++e) atomicAdd(&s2[bg * D_ + e], acc[e]);
    }

    // x1 for own pixel: y = gx*xh*xw, LayerNorm over 32 channels
    const float4* vp  = (const float4*)(base + ((size_t)h * W_ + w) * C_);
    const float4* xhp = (const float4*)(xh + ((size_t)bg * H_ + h) * D_);
    const float4* xwp = (const float4*)(xw + ((size_t)bg * W_ + w) * D_);
    float y[D_];
    float mu = 0.f;
    #pragma unroll
    for (int q = 0; q < 8; ++q) {
        float4 t = vp[q], a = xhp[q], bq = xwp[q];
        y[4 * q + 0] = t.x * a.x * bq.x;
        y[4 * q + 1] = t.y * a.y * bq.y;
        y[4 * q + 2] = t.z * a.z * bq.z;
        y[4 * q + 3] = t.w * a.w * bq.w;
        mu += y[4 * q + 0] + y[4 * q + 1] + y[4 * q + 2] + y[4 * q + 3];
    }
    mu *= (1.0f / D_);
    float var = 0.f;
    #pragma unroll
    for (int c = 0; c < D_; ++c) { float dlt = y[c] - mu; var += dlt * dlt; }
    var *= (1.0f / D_);
    float rs = rsqrtf(var + LN_EPS_);
    #pragma unroll
    for (int q = 0; q < 8; ++q) {
        float4 gq = ((const float4*)gamma)[q];
        float4 bt = ((const float4*)beta)[q];
        y[4 * q + 0] = (y[4 * q + 0] - mu) * rs * gq.x + bt.x;
        y[4 * q + 1] = (y[4 * q + 1] - mu) * rs * gq.y + bt.y;
        y[4 * q + 2] = (y[4 * q + 2] - mu) * rs * gq.z + bt.z;
        y[4 * q + 3] = (y[4 * q + 3] - mu) * rs * gq.w + bt.w;
    }
    #pragma unroll
    for (int e = 0; e < D_; ++e) {
        float v = y[e];
        v += __shfl_xor(v, 1);  v += __shfl_xor(v, 2);  v += __shfl_xor(v, 4);
        v += __shfl_xor(v, 8);  v += __shfl_xor(v, 16); v += __shfl_xor(v, 32);
        y[e] = v;
    }
    if (lane == 0) {
        #pragma unroll
        for (int e = 0; e < D_; ++e) atomicAdd(&s1[bg * D_ + e], y[e]);
    }
}

// ---------------------------------------------------------------------------
// K4: per-bg channel softmax of s1/3072 and s2/3072. grid = BG, 64 threads.
// ---------------------------------------------------------------------------
__global__ __launch_bounds__(64) void k4_softmax(const float* __restrict__ s1,
                                                 const float* __restrict__ s2,
                                                 float* __restrict__ x11,
                                                 float* __restrict__ x21)
{
    int bg = blockIdx.x;
    int lane = threadIdx.x;
    const float* s = (lane < 32) ? s1 : s2;
    float* o = (lane < 32) ? x11 : x21;
    int c = lane & 31;
    float v = s[bg * D_ + c] * (1.0f / (float)NPIX_);
    float m = v;
    m = fmaxf(m, __shfl_xor(m, 1));  m = fmaxf(m, __shfl_xor(m, 2));
    m = fmaxf(m, __shfl_xor(m, 4));  m = fmaxf(m, __shfl_xor(m, 8));
    m = fmaxf(m, __shfl_xor(m, 16));
    float e = expf(v - m);
    float sm = e;
    sm += __shfl_xor(sm, 1);  sm += __shfl_xor(sm, 2);
    sm += __shfl_xor(sm, 4);  sm += __shfl_xor(sm, 8);
    sm += __shfl_xor(sm, 16);
    o[bg * D_ + c] = e / sm;
}

// ---------------------------------------------------------------------------
// K5: final gate. Recompute x1 per pixel, read x2, gate = sigmoid(x11.x2 +
// x21.x1), out = gx * gate. Same mapping as K3.
// ---------------------------------------------------------------------------
__global__ __launch_bounds__(192) void k5_final(const float* __restrict__ x,
                                                const float* __restrict__ xh,
                                                const float* __restrict__ xw,
                                                const float* __restrict__ gamma,
                                                const float* __restrict__ beta,
                                                const float* __restrict__ x2,
                                                const float* __restrict__ x11,
                                                const float* __restrict__ x21,
                                                float* __restrict__ out)
{
    int bi = blockIdx.x;
    int bg = bi >> 4;
    int h0 = (bi & 15) << 2;
    int tid = threadIdx.x;
    int r = tid / W_;
    int w = tid % W_;
    int h = h0 + r;
    int b = bg >> 3, gi = bg & 7;
    size_t pixoff = (size_t)b * H_ * W_ * C_ + ((size_t)h * W_ + w) * C_ + gi * D_;

    const float4* vp  = (const float4*)(x + pixoff);
    const float4* xhp = (const float4*)(xh + ((size_t)bg * H_ + h) * D_);
    const float4* xwp = (const float4*)(xw + ((size_t)bg * W_ + w) * D_);

    float v[D_], y[D_];
    float mu = 0.f;
    #pragma unroll
    for (int q = 0; q < 8; ++q) {
        float4 t = vp[q], a = xhp[q], bq = xwp[q];
        v[4 * q + 0] = t.x; v[4 * q + 1] = t.y; v[4 * q + 2] = t.z; v[4 * q + 3] = t.w;
        y[4 * q + 0] = t.x * a.x * bq.x;
        y[4 * q + 1] = t.y * a.y * bq.y;
        y[4 * q + 2] = t.z * a.z * bq.z;
        y[4 * q + 3] = t.w * a.w * bq.w;
        mu += y[4 * q + 0] + y[4 * q + 1] + y[4 * q + 2] + y[4 * q + 3];
    }
    mu *= (1.0f / D_);
    float var = 0.f;
    #pragma unroll
    for (int c = 0; c < D_; ++c) { float dlt = y[c] - mu; var += dlt * dlt; }
    var *= (1.0f / D_);
    float rs = rsqrtf(var + LN_EPS_);

    const float4* x2p = (const float4*)(x2 + (((size_t)bg * H_ + h) * W_ + w) * D_);
    float w1 = 0.f, w2 = 0.f;
    #pragma unroll
    for (int q = 0; q < 8; ++q) {
        float4 gq  = ((const float4*)gamma)[q];
        float4 bt  = ((const float4*)beta)[q];
        float4 a11 = ((const float4*)x11)[bg * 8 + q];
        float4 a21 = ((const float4*)x21)[bg * 8 + q];
        float4 xv  = x2p[q];
        float x1a = (y[4 * q + 0] - mu) * rs * gq.x + bt.x;
        float x1b = (y[4 * q + 1] - mu) * rs * gq.y + bt.y;
        float x1c = (y[4 * q + 2] - mu) * rs * gq.z + bt.z;
        float x1d = (y[4 * q + 3] - mu) * rs * gq.w + bt.w;
        w1 += a11.x * xv.x + a11.y * xv.y + a11.z * xv.z + a11.w * xv.w;
        w2 += a21.x * x1a + a21.y * x1b + a21.z * x1c + a21.w * x1d;
    }
    float gate = sigmoidf_(w1 + w2);

    float4* op = (float4*)(out + pixoff);
    #pragma unroll
    for (int q = 0; q < 8; ++q) {
        float4 t;
        t.x = v[4 * q + 0] * gate; t.y = v[4 * q + 1] * gate;
        t.z = v[4 * q + 2] * gate; t.w = v[4 * q + 3] * gate;
        op[q] = t;
    }
}

extern "C" void kernel_launch(void* const* d_in, const int* in_sizes, int n_in,
                              void* d_out, int out_size, void* d_ws, size_t ws_size,
                              hipStream_t stream)
{
    const float* x     = (const float*)d_in[0];
    const float* w1    = (const float*)d_in[1];
    const float* b1    = (const float*)d_in[2];
    const float* w3    = (const float*)d_in[3];
    const float* b3    = (const float*)d_in[4];
    const float* gamma = (const float*)d_in[5];
    const float* beta  = (const float*)d_in[6];

    float* ws  = (float*)d_ws;
    float* x2  = ws;                                   // BG*H*W*32 = 25165824 floats
    float* xh  = ws + (size_t)BG_ * H_ * W_ * D_;      // BG*H*32
    float* xw  = xh + (size_t)BG_ * H_ * D_;           // BG*W*32
    float* s1  = xw + (size_t)BG_ * W_ * D_;           // BG*32
    float* s2  = s1 + BG_ * D_;
    float* x11 = s2 + BG_ * D_;
    float* x21 = x11 + BG_ * D_;

    hipMemsetAsync(s1, 0, 2 * BG_ * D_ * sizeof(float), stream);

    k1_means<<<BG_, 256, 0, stream>>>(x, w1, b1, xh, xw);
    k3_conv<<<BG_ * (H_ / 4), 192, 0, stream>>>(x, w3, b3, xh, xw, gamma, beta, x2, s1, s2);
    k4_softmax<<<BG_, 64, 0, stream>>>(s1, s2, x11, x21);
    k5_final<<<BG_ * (H_ / 4), 192, 0, stream>>>(x, xh, xw, gamma, beta, x2, x11, x21,
                                                 (float*)d_out);
}

// Round 3
// 343.136 us; speedup vs baseline: 2.0740x; 2.0740x over previous
//
#include <hip/hip_runtime.h>
#include <math.h>

#define B_ 32
#define H_ 64
#define W_ 48
#define C_ 256
#define G_ 8
#define D_ 32
#define BG_ (B_*G_)          // 256
#define LN_EPS_ 1e-3f
#define NPIX_ (H_*W_)        // 3072

typedef short bf16x8 __attribute__((ext_vector_type(8)));
typedef float f32x4 __attribute__((ext_vector_type(4)));

__device__ __forceinline__ float sigmoidf_(float v) { return 1.0f / (1.0f + expf(-v)); }

// fp32 -> bf16 round-to-nearest-even
__device__ __forceinline__ unsigned short f2bf(float f) {
    unsigned u = __float_as_uint(f);
    u = u + 0x7fffu + ((u >> 16) & 1u);
    return (unsigned short)(u >> 16);
}
__device__ __forceinline__ float bflo(unsigned u) { return __uint_as_float(u << 16); }
__device__ __forceinline__ float bfhi(unsigned u) { return __uint_as_float(u & 0xffff0000u); }

// ---------------------------------------------------------------------------
// K0: transpose+convert conv3x3 weights to bf16, layout wbf[tap][e][d]
// ---------------------------------------------------------------------------
__global__ __launch_bounds__(256) void k0_prep(const float* __restrict__ w3,
                                               unsigned short* __restrict__ wbf)
{
    int i = blockIdx.x * 256 + threadIdx.x;
    if (i < 9 * D_ * D_) {
        int t = i >> 10;
        int rem = i & 1023;
        int e = rem >> 5, d = rem & 31;
        wbf[i] = f2bf(w3[((t << 5) + d) * D_ + e]);
    }
}

// ---------------------------------------------------------------------------
// K1: one-pass H/W means, then 1x1 conv + sigmoid -> xh[BG][64][32], xw[BG][48][32]
// grid = BG, 256 threads. Reads x exactly once (100 MB total).
// ---------------------------------------------------------------------------
__global__ __launch_bounds__(256) void k1_means(const float* __restrict__ x,
                                                const float* __restrict__ w1,
                                                const float* __restrict__ b1,
                                                float* __restrict__ xh,
                                                float* __restrict__ xw)
{
    int bg = blockIdx.x;
    int b = bg >> 3, gi = bg & 7;
    const float* xp = x + (size_t)b * H_ * W_ * C_ + gi * D_;
    __shared__ float mh[H_][D_];   // raw row sums (over w)
    __shared__ float mw[W_][D_];   // col means (over h)
    __shared__ float wls[D_ * D_];
    int t = threadIdx.x;
    int c = t & 31;
    int wg = t >> 5;               // 0..7, owns w = wg*6 + j, j=0..5
    for (int i = t; i < D_ * D_; i += 256) wls[i] = w1[i];
    for (int i = t; i < H_ * D_; i += 256) mh[i >> 5][i & 31] = 0.f;
    __syncthreads();

    float colp[6] = {0.f, 0.f, 0.f, 0.f, 0.f, 0.f};
    for (int h = 0; h < H_; ++h) {
        const float* row = xp + (size_t)h * W_ * C_;
        float rp = 0.f;
        #pragma unroll
        for (int j = 0; j < 6; ++j) {
            float v = row[(size_t)(wg * 6 + j) * C_ + c];
            rp += v;
            colp[j] += v;
        }
        rp += __shfl_xor(rp, 32);
        if ((t & 63) < 32) atomicAdd(&mh[h][c], rp);
    }
    #pragma unroll
    for (int j = 0; j < 6; ++j) mw[wg * 6 + j][c] = colp[j] * (1.0f / H_);
    __syncthreads();

    for (int i = t; i < (H_ + W_) * D_; i += 256) {
        int pos = i >> 5, e = i & 31;
        const float* m = (pos < H_) ? mh[pos] : mw[pos - H_];
        float scale = (pos < H_) ? (1.0f / W_) : 1.0f;
        float dot = 0.f;
        #pragma unroll
        for (int d = 0; d < D_; ++d) dot += m[d] * wls[d * D_ + e];
        float s = sigmoidf_(b1[e] + dot * scale);
        if (pos < H_) xh[((size_t)bg * H_ + pos) * D_ + e] = s;
        else          xw[((size_t)bg * W_ + (pos - H_)) * D_ + e] = s;
    }
}

// ---------------------------------------------------------------------------
// K3: MFMA 3x3 conv -> x2 (bf16) + fused x1/LN pass on the LDS tile.
// grid = BG*4 (16 rows each), 256 threads (4 waves).
// LDS tile: 18 rows x 50 padded cols x 32 ch, bf16, XOR-swizzled (px&7)<<4.
// ---------------------------------------------------------------------------
#define SROWS 18
#define SPXL 50
#define ROWB (SPXL * 64)   // 3200 bytes per LDS row

__global__ __launch_bounds__(256) void k3_conv(const float* __restrict__ x,
                                               const unsigned short* __restrict__ wbf,
                                               const float* __restrict__ b3,
                                               const float* __restrict__ xh,
                                               const float* __restrict__ xw,
                                               const float* __restrict__ gamma,
                                               const float* __restrict__ beta,
                                               unsigned short* __restrict__ x2,
                                               float* __restrict__ s1,
                                               float* __restrict__ s2)
{
    __shared__ unsigned short sbuf[SROWS * SPXL * 32];   // 57600 B
    int bi = blockIdx.x;
    int bg = bi >> 2;
    int h0 = (bi & 3) << 4;            // 16 rows per block
    int b = bg >> 3, gi = bg & 7;
    const float* base = x + (size_t)b * H_ * W_ * C_ + gi * D_;
    int t = threadIdx.x;
    int lane = t & 63;
    int wv = t >> 6;

    // --- weight fragments in registers: 9 taps x 2 N-halves
    const int e0 = lane & 15;
    const int ko = (lane >> 4) << 3;    // k-chunk start (0,8,16,24)
    bf16x8 wf[9][2];
    #pragma unroll
    for (int tp = 0; tp < 9; ++tp)
        #pragma unroll
        for (int n = 0; n < 2; ++n)
            wf[tp][n] = *(const bf16x8*)(const void*)(wbf + (((tp << 5) + (n << 4) + e0) << 5) + ko);
    float be0 = b3[e0], be1 = b3[e0 + 16];

    // --- zero the two padding columns (px=0 and px=49)
    if (t < SROWS * 2 * 4) {
        int r = t >> 3, side = (t >> 2) & 1, slot = t & 3;
        int px = side ? (SPXL - 1) : 0;
        int addr = r * ROWB + ((((px << 6) + (slot << 4))) ^ ((px & 7) << 4));
        *(uint4*)((char*)sbuf + addr) = make_uint4(0, 0, 0, 0);
    }

    // --- stage 18 rows x 48 px x 32 ch as bf16 (rows outside image -> 0)
    const int NIDX = SROWS * 48 * 8;    // float4 chunks
    for (int i = t; i < NIDX; i += 256) {
        int r = i / 384;
        int rem = i - r * 384;
        int w = rem >> 3, c4 = rem & 7;
        int hh = h0 - 1 + r;
        unsigned u0 = 0, u1 = 0;
        if (hh >= 0 && hh < H_) {
            float4 v = *(const float4*)(base + ((size_t)hh * W_ + w) * C_ + (c4 << 2));
            u0 = (unsigned)f2bf(v.x) | ((unsigned)f2bf(v.y) << 16);
            u1 = (unsigned)f2bf(v.z) | ((unsigned)f2bf(v.w) << 16);
        }
        int px = w + 1;
        int addr = r * ROWB + ((((px << 6) + (c4 << 3))) ^ ((px & 7) << 4));
        *(uint2*)((char*)sbuf + addr) = make_uint2(u0, u1);
    }
    __syncthreads();

    // --- MFMA phase: each wave does 4 rows x 3 M-tiles of 16 pixels
    float s2p0 = 0.f, s2p1 = 0.f;
    for (int q = 0; q < 4; ++q) {
        int r = (wv << 2) + q;          // local output row 0..15
        int h = h0 + r;
        for (int m = 0; m < 3; ++m) {
            int w0 = m << 4;
            f32x4 acc0 = {be0, be0, be0, be0};
            f32x4 acc1 = {be1, be1, be1, be1};
            #pragma unroll
            for (int dh = 0; dh < 3; ++dh) {
                int srow = r + dh;
                #pragma unroll
                for (int dw = 0; dw < 3; ++dw) {
                    int px = w0 + (lane & 15) + dw;
                    int addr = srow * ROWB + ((((px << 6) + ((lane >> 4) << 4))) ^ ((px & 7) << 4));
                    bf16x8 a = *(const bf16x8*)(const void*)((const char*)sbuf + addr);
                    acc0 = __builtin_amdgcn_mfma_f32_16x16x32_bf16(a, wf[dh * 3 + dw][0], acc0, 0, 0, 0);
                    acc1 = __builtin_amdgcn_mfma_f32_16x16x32_bf16(a, wf[dh * 3 + dw][1], acc1, 0, 0, 0);
                }
            }
            // D layout: col=lane&15 (=e), row=(lane>>4)*4+reg (=pixel in tile)
            #pragma unroll
            for (int rg = 0; rg < 4; ++rg) {
                int pw = w0 + ((lane >> 4) << 2) + rg;
                size_t off = (((size_t)bg * H_ + h) * W_ + pw) * D_;
                x2[off + e0]      = f2bf(acc0[rg]);
                x2[off + e0 + 16] = f2bf(acc1[rg]);
                s2p0 += acc0[rg];
                s2p1 += acc1[rg];
            }
        }
    }
    // s2 reduce: lanes sharing e0 are lane, lane^16, lane^32, lane^48
    s2p0 += __shfl_xor(s2p0, 16); s2p0 += __shfl_xor(s2p0, 32);
    s2p1 += __shfl_xor(s2p1, 16); s2p1 += __shfl_xor(s2p1, 32);
    if (lane < 16) {
        atomicAdd(&s2[bg * D_ + e0], s2p0);
        atomicAdd(&s2[bg * D_ + e0 + 16], s2p1);
    }

    // --- x1 phase: y = gx*xh*xw, LN, accumulate s1. 768 px, 3 per thread.
    float s1p[32];
    #pragma unroll
    for (int c = 0; c < 32; ++c) s1p[c] = 0.f;
    #pragma unroll
    for (int pp = 0; pp < 3; ++pp) {
        int pl = t + (pp << 8);
        int r = pl / 48;
        int w = pl - r * 48;
        int srow = r + 1;
        int px = w + 1;
        float v[32];
        #pragma unroll
        for (int slot = 0; slot < 4; ++slot) {
            int addr = srow * ROWB + ((((px << 6) + (slot << 4))) ^ ((px & 7) << 4));
            uint4 u = *(const uint4*)((const char*)sbuf + addr);
            v[slot * 8 + 0] = bflo(u.x); v[slot * 8 + 1] = bfhi(u.x);
            v[slot * 8 + 2] = bflo(u.y); v[slot * 8 + 3] = bfhi(u.y);
            v[slot * 8 + 4] = bflo(u.z); v[slot * 8 + 5] = bfhi(u.z);
            v[slot * 8 + 6] = bflo(u.w); v[slot * 8 + 7] = bfhi(u.w);
        }
        const float4* ph4 = (const float4*)(xh + (((size_t)bg * H_) + h0 + r) * D_);
        const float4* pw4 = (const float4*)(xw + (((size_t)bg * W_) + w) * D_);
        float y[32];
        float mu = 0.f;
        #pragma unroll
        for (int c4 = 0; c4 < 8; ++c4) {
            float4 a = ph4[c4], bq = pw4[c4];
            y[4 * c4 + 0] = v[4 * c4 + 0] * a.x * bq.x;
            y[4 * c4 + 1] = v[4 * c4 + 1] * a.y * bq.y;
            y[4 * c4 + 2] = v[4 * c4 + 2] * a.z * bq.z;
            y[4 * c4 + 3] = v[4 * c4 + 3] * a.w * bq.w;
            mu += y[4 * c4 + 0] + y[4 * c4 + 1] + y[4 * c4 + 2] + y[4 * c4 + 3];
        }
        mu *= (1.0f / D_);
        float var = 0.f;
        #pragma unroll
        for (int c = 0; c < 32; ++c) { float dl = y[c] - mu; var += dl * dl; }
        var *= (1.0f / D_);
        float rs = rsqrtf(var + LN_EPS_);
        #pragma unroll
        for (int c4 = 0; c4 < 8; ++c4) {
            float4 gq = ((const float4*)gamma)[c4];
            float4 bt = ((const float4*)beta)[c4];
            s1p[4 * c4 + 0] += (y[4 * c4 + 0] - mu) * rs * gq.x + bt.x;
            s1p[4 * c4 + 1] += (y[4 * c4 + 1] - mu) * rs * gq.y + bt.y;
            s1p[4 * c4 + 2] += (y[4 * c4 + 2] - mu) * rs * gq.z + bt.z;
            s1p[4 * c4 + 3] += (y[4 * c4 + 3] - mu) * rs * gq.w + bt.w;
        }
    }
    #pragma unroll
    for (int c = 0; c < 32; ++c) {
        float vv = s1p[c];
        vv += __shfl_xor(vv, 1);  vv += __shfl_xor(vv, 2);  vv += __shfl_xor(vv, 4);
        vv += __shfl_xor(vv, 8);  vv += __shfl_xor(vv, 16); vv += __shfl_xor(vv, 32);
        s1p[c] = vv;
    }
    if (lane == 0) {
        #pragma unroll
        for (int c = 0; c < 32; ++c) atomicAdd(&s1[bg * D_ + c], s1p[c]);
    }
}

// ---------------------------------------------------------------------------
// K4: per-bg channel softmax of s1/3072 and s2/3072.
// ---------------------------------------------------------------------------
__global__ __launch_bounds__(64) void k4_softmax(const float* __restrict__ s1,
                                                 const float* __restrict__ s2,
                                                 float* __restrict__ x11,
                                                 float* __restrict__ x21)
{
    int bg = blockIdx.x;
    int lane = threadIdx.x;
    const float* s = (lane < 32) ? s1 : s2;
    float* o = (lane < 32) ? x11 : x21;
    int c = lane & 31;
    float v = s[bg * D_ + c] * (1.0f / (float)NPIX_);
    float m = v;
    m = fmaxf(m, __shfl_xor(m, 1));  m = fmaxf(m, __shfl_xor(m, 2));
    m = fmaxf(m, __shfl_xor(m, 4));  m = fmaxf(m, __shfl_xor(m, 8));
    m = fmaxf(m, __shfl_xor(m, 16));
    float e = expf(v - m);
    float sm = e;
    sm += __shfl_xor(sm, 1);  sm += __shfl_xor(sm, 2);
    sm += __shfl_xor(sm, 4);  sm += __shfl_xor(sm, 8);
    sm += __shfl_xor(sm, 16);
    o[bg * D_ + c] = e / sm;
}

// ---------------------------------------------------------------------------
// K5: final gate. Recompute x1 (fp32), read x2 (bf16), out = gx * gate.
// ---------------------------------------------------------------------------
__global__ __launch_bounds__(192) void k5_final(const float* __restrict__ x,
                                                const float* __restrict__ xh,
                                                const float* __restrict__ xw,
                                                const float* __restrict__ gamma,
                                                const float* __restrict__ beta,
                                                const unsigned short* __restrict__ x2,
                                                const float* __restrict__ x11,
                                                const float* __restrict__ x21,
                                                float* __restrict__ out)
{
    int bi = blockIdx.x;
    int bg = bi >> 4;
    int h0 = (bi & 15) << 2;
    int tid = threadIdx.x;
    int r = tid / W_;
    int w = tid % W_;
    int h = h0 + r;
    int b = bg >> 3, gi = bg & 7;
    size_t pixoff = (size_t)b * H_ * W_ * C_ + ((size_t)h * W_ + w) * C_ + gi * D_;

    const float4* vp  = (const float4*)(x + pixoff);
    const float4* xhp = (const float4*)(xh + ((size_t)bg * H_ + h) * D_);
    const float4* xwp = (const float4*)(xw + ((size_t)bg * W_ + w) * D_);

    float v[D_], y[D_];
    float mu = 0.f;
    #pragma unroll
    for (int q = 0; q < 8; ++q) {
        float4 tq = vp[q], a = xhp[q], bq = xwp[q];
        v[4 * q + 0] = tq.x; v[4 * q + 1] = tq.y; v[4 * q + 2] = tq.z; v[4 * q + 3] = tq.w;
        y[4 * q + 0] = tq.x * a.x * bq.x;
        y[4 * q + 1] = tq.y * a.y * bq.y;
        y[4 * q + 2] = tq.z * a.z * bq.z;
        y[4 * q + 3] = tq.w * a.w * bq.w;
        mu += y[4 * q + 0] + y[4 * q + 1] + y[4 * q + 2] + y[4 * q + 3];
    }
    mu *= (1.0f / D_);
    float var = 0.f;
    #pragma unroll
    for (int c = 0; c < D_; ++c) { float dl = y[c] - mu; var += dl * dl; }
    var *= (1.0f / D_);
    float rs = rsqrtf(var + LN_EPS_);

    const uint4* x2q = (const uint4*)(x2 + (((size_t)bg * H_ + h) * W_ + w) * D_);
    float w1 = 0.f, w2 = 0.f;
    #pragma unroll
    for (int j = 0; j < 4; ++j) {                 // 8 channels per uint4
        uint4 u = x2q[j];
        float xv[8];
        xv[0] = bflo(u.x); xv[1] = bfhi(u.x); xv[2] = bflo(u.y); xv[3] = bfhi(u.y);
        xv[4] = bflo(u.z); xv[5] = bfhi(u.z); xv[6] = bflo(u.w); xv[7] = bfhi(u.w);
        #pragma unroll
        for (int k = 0; k < 8; ++k) {
            int c = j * 8 + k;
            float x1v = (y[c] - mu) * rs * gamma[c] + beta[c];
            w1 += x11[bg * D_ + c] * xv[k];
            w2 += x21[bg * D_ + c] * x1v;
        }
    }
    float gate = sigmoidf_(w1 + w2);

    float4* op = (float4*)(out + pixoff);
    #pragma unroll
    for (int q = 0; q < 8; ++q) {
        float4 tq;
        tq.x = v[4 * q + 0] * gate; tq.y = v[4 * q + 1] * gate;
        tq.z = v[4 * q + 2] * gate; tq.w = v[4 * q + 3] * gate;
        op[q] = tq;
    }
}

extern "C" void kernel_launch(void* const* d_in, const int* in_sizes, int n_in,
                              void* d_out, int out_size, void* d_ws, size_t ws_size,
                              hipStream_t stream)
{
    const float* x     = (const float*)d_in[0];
    const float* w1    = (const float*)d_in[1];
    const float* b1    = (const float*)d_in[2];
    const float* w3    = (const float*)d_in[3];
    const float* b3    = (const float*)d_in[4];
    const float* gamma = (const float*)d_in[5];
    const float* beta  = (const float*)d_in[6];

    char* wsb = (char*)d_ws;
    unsigned short* x2  = (unsigned short*)wsb;                    // 50331648 B
    float* xh  = (float*)(wsb + 50331648);                          // 2097152 B
    float* xw  = (float*)(wsb + 52428800);                          // 1572864 B
    float* s1  = (float*)(wsb + 54001664);                          // 32768 B
    float* s2  = (float*)(wsb + 54034432);                          // 32768 B
    float* x11 = (float*)(wsb + 54067200);                          // 32768 B
    float* x21 = (float*)(wsb + 54099968);                          // 32768 B
    unsigned short* wbf = (unsigned short*)(wsb + 54132736);        // 18432 B

    hipMemsetAsync(s1, 0, 65536, stream);   // s1 + s2

    k0_prep<<<36, 256, 0, stream>>>(w3, wbf);
    k1_means<<<BG_, 256, 0, stream>>>(x, w1, b1, xh, xw);
    k3_conv<<<BG_ * 4, 256, 0, stream>>>(x, wbf, b3, xh, xw, gamma, beta, x2, s1, s2);
    k4_softmax<<<BG_, 64, 0, stream>>>(s1, s2, x11, x21);
    k5_final<<<BG_ * (H_ / 4), 192, 0, stream>>>(x, xh, xw, gamma, beta, x2, x11, x21,
                                                 (float*)d_out);
}